// Round 5
// baseline (215.094 us; speedup 1.0000x reference)
//
#include <hip/hip_runtime.h>
#include <cstdint>

typedef __attribute__((ext_vector_type(8))) short short8;
typedef __attribute__((ext_vector_type(4))) float floatx4;

#define TWO_PI 6.283185307179586f

__device__ __forceinline__ unsigned short f2bf(float f) {
  union { float f; uint32_t u; } c; c.f = f;
  uint32_t u = c.u;
  u += 0x7FFFu + ((u >> 16) & 1u);   // RNE
  return (unsigned short)(u >> 16);
}
__device__ __forceinline__ uint32_t packbf(float re, float im) {
  return (uint32_t)f2bf(re) | ((uint32_t)f2bf(im) << 16);
}

// ---------------------------------------------------------------------------
// Four-step DFT convolution, N = 65536 = 256 x 256, t = c + 256 r, k = k1 + 256 k2.
// z_s = x[2s] + i x[2s+1].  All 256-pt DFT stages are real bf16 MFMA GEMMs via
// the 2x2 rotation embedding.
// ---------------------------------------------------------------------------

// Merged prep: blocks [0,3072) build A1..A4; [3072,4096) transpose/pack x->Zp;
// [4096,4352) compute Gw[k1][c] (root-table inner loop); [4352,4608) Tw[k1][c].
__global__ __launch_bounds__(256) void prep_all(
    const float* __restrict__ x, const float* __restrict__ filt,
    unsigned short* __restrict__ A1, unsigned short* __restrict__ A2,
    unsigned short* __restrict__ A3, unsigned short* __restrict__ A4,
    uint32_t* __restrict__ Zp, float2* __restrict__ Gw,
    float2* __restrict__ Tw) {
  __shared__ float2 roots[256];
  const int bid = blockIdx.x;
  const int tid = threadIdx.x;
  const float w256 = TWO_PI / 256.0f;
  if (bid < 3072) {
    int idx = bid * 256 + tid;
    if (idx < 131072) {                       // A1 [512x256], E-(k1 r/256)
      int col = idx & 255, row = idx >> 8;
      int k1 = row >> 1, d = row & 1, r = col >> 1, e = col & 1;
      float th = (float)((k1 * r) & 255) * w256;
      float sn, cs; __sincosf(th, &sn, &cs);
      A1[idx] = f2bf(d == 0 ? (e == 0 ? cs : sn) : (e == 0 ? -sn : cs));
    } else if (idx < 393216) {                // A2 [512x512], E-(k2 c/256)
      int j = idx - 131072;
      int col = j & 511, row = j >> 9;
      int k2 = row >> 1, d = row & 1, cc = col >> 1, e = col & 1;
      float th = (float)((k2 * cc) & 255) * w256;
      float sn, cs; __sincosf(th, &sn, &cs);
      A2[j] = f2bf(d == 0 ? (e == 0 ? cs : sn) : (e == 0 ? -sn : cs));
    } else if (idx < 655360) {                // A3 [512x512], rows 2c+d, E+(k2 c/256)
      int j = idx - 393216;
      int col = j & 511, row = j >> 9;
      int cc = row >> 1, d = row & 1, k2 = col >> 1, e = col & 1;
      float th = (float)((k2 * cc) & 255) * w256;
      float sn, cs; __sincosf(th, &sn, &cs);
      A3[j] = f2bf(d == 0 ? (e == 0 ? cs : -sn) : (e == 0 ? sn : cs));
    } else {                                  // A4 [256x512], rows 2r+d, E+(k1 r/256)
      int j = idx - 655360;
      int col = j & 511, row = j >> 9;
      int r = row >> 1, d = row & 1, k1 = col >> 1, e = col & 1;
      float th = (float)((k1 * r) & 255) * w256;
      float sn, cs; __sincosf(th, &sn, &cs);
      A4[j] = f2bf(d == 0 ? (e == 0 ? cs : -sn) : (e == 0 ? sn : cs));
    }
  } else if (bid < 4096) {                    // Zp[(s*256+c)][r] packed bf16 pair
    int b2 = bid - 3072;                      // 1024 blocks: (s, r-chunk of 16)
    int s = b2 >> 3, rq = b2 & 7;
    const float* x0 = x + (size_t)(2 * s) * 32768;
    const float* x1 = x0 + 32768;
    uint32_t v[16];
    #pragma unroll
    for (int rr = 0; rr < 16; ++rr) {
      int t = tid + 256 * (rq * 16 + rr);
      v[rr] = (uint32_t)f2bf(x0[t]) | ((uint32_t)f2bf(x1[t]) << 16);
    }
    uint32_t* dst = Zp + (size_t)(s * 256 + tid) * 128 + rq * 16;
    #pragma unroll
    for (int j = 0; j < 16; j += 4)
      *(uint4*)(dst + j) = make_uint4(v[j], v[j + 1], v[j + 2], v[j + 3]);
  } else if (bid < 4352) {                    // Gw[k1][c], fp32, root-table loop
    int k1 = bid - 4096, c = tid;
    { float sn, cs; __sincosf((float)tid * w256, &sn, &cs);
      roots[tid] = make_float2(cs, sn); }     // identical values to __sincosf(j*w256)
    __syncthreads();
    float ar = 0.f, ai = 0.f;
    for (int r = 0; r < 128; ++r) {
      float v = filt[c + 256 * r];
      float2 wv = roots[(k1 * r) & 255];      // wave-uniform -> LDS broadcast
      ar += v * wv.x; ai -= v * wv.y;
    }
    float th = (float)((k1 * c) & 65535) * (TWO_PI / 65536.0f);
    float sn, cs; __sincosf(th, &sn, &cs);
    Gw[(k1 << 8) + c] = make_float2(ar * cs + ai * sn, ai * cs - ar * sn);
  } else {                                    // Tw[k1][c] = (cos, sin) of k1*c/65536
    int k1 = bid - 4352, c = tid;
    float th = (float)((k1 * c) & 65535) * (TWO_PI / 65536.0f);
    float sn, cs; __sincosf(th, &sn, &cs);
    Tw[(k1 << 8) + c] = make_float2(cs, sn);
  }
}

// WtT[k2][k1] = sum_c Gw[k1][c] E-(k2 c/256)   (fp32, TRANSPOSED for coalesced
// epilogue).  Root-table inner loop: no sincos in the 256-iter chain.
__global__ __launch_bounds__(256) void prep_wb(const float2* __restrict__ Gw,
                                               float2* __restrict__ WtT) {
  __shared__ float2 roots[256];
  int k1 = blockIdx.x, k2 = threadIdx.x;
  { float sn, cs; __sincosf((float)k2 * (TWO_PI / 256.0f), &sn, &cs);
    roots[k2] = make_float2(cs, sn); }
  __syncthreads();
  float ar = 0.f, ai = 0.f;
  for (int c = 0; c < 256; ++c) {
    float2 g = Gw[(k1 << 8) + c];             // wave-uniform broadcast
    float2 wv = roots[(k2 * c) & 255];        // LDS gather
    ar += g.x * wv.x + g.y * wv.y;
    ai += g.y * wv.x - g.x * wv.y;
  }
  WtT[(k2 << 8) + k1] = make_float2(ar, ai);
}

// 128^2-tile stage (MODES 1,4): R0/R3-proven loop, 256 threads, BK=64, 2-dbuf.
// MODE 1: *Tw(E-) -> G2[(s,k1)][c].   MODE 4: write y (scale 1/65536).
template <int MODE, int KITERS>
__global__ __launch_bounds__(256, 2) void dft_stage(
    const unsigned short* __restrict__ Af,
    const unsigned short* __restrict__ Bd,
    uint32_t* __restrict__ outp,
    float* __restrict__ yout,
    const float2* __restrict__ tab) {
  __shared__ unsigned short Sm[32768];        // As0|As1|Bs0|Bs1, 16 KB each
  constexpr int KP = KITERS * 64;

  const int mt = blockIdx.x >> 8;
  const int nt = blockIdx.x & 255;
  const int m0 = mt * 128, n0 = nt * 128;

  const int tid = threadIdx.x;
  const int w = tid >> 6, lane = tid & 63;
  const int qlo = lane & 15, qhi = lane >> 4;
  const int wr = w >> 1, wc = w & 1;
  const int r8 = lane >> 3, pl = lane & 7, sj = pl ^ r8, q3 = qlo & 7;

  floatx4 acc[4][4];
  #pragma unroll
  for (int i = 0; i < 4; ++i)
    #pragma unroll
    for (int j = 0; j < 4; ++j) acc[i][j] = (floatx4){0.f, 0.f, 0.f, 0.f};

  auto issue = [&](int it, int buf) {
    const int k0 = it * 64;
    unsigned short* Asb = Sm + buf * 8192;
    unsigned short* Bsb = Sm + 16384 + buf * 8192;
    #pragma unroll
    for (int q = 0; q < 4; ++q) {
      const int R = w * 32 + q * 8 + r8;
      const unsigned short* gA = Af + (size_t)(m0 + R) * KP + k0 + sj * 8;
      const unsigned short* gB = Bd + (size_t)(n0 + R) * KP + k0 + sj * 8;
      __builtin_amdgcn_global_load_lds(
          (const __attribute__((address_space(1))) uint32_t*)gA,
          (__attribute__((address_space(3))) uint32_t*)&Asb[(w * 32 + q * 8) * 64], 16, 0, 0);
      __builtin_amdgcn_global_load_lds(
          (const __attribute__((address_space(1))) uint32_t*)gB,
          (__attribute__((address_space(3))) uint32_t*)&Bsb[(w * 32 + q * 8) * 64], 16, 0, 0);
    }
  };

  issue(0, 0);
  for (int it = 0; it < KITERS; ++it) {
    __syncthreads();                          // drains prev iter's prefetch (vmcnt)
    if (it + 1 < KITERS) issue(it + 1, (it + 1) & 1);
    const unsigned short* Ab = Sm + (it & 1) * 8192;
    const unsigned short* Bb = Sm + 16384 + (it & 1) * 8192;
    #pragma unroll
    for (int ks = 0; ks < 2; ++ks) {
      short8 a[4], bb[4];
      #pragma unroll
      for (int im = 0; im < 4; ++im) {
        const int R = wr * 64 + im * 16 + qlo;
        a[im] = *(const short8*)&Ab[R * 64 + (((ks * 4 + qhi) ^ q3) << 3)];
      }
      #pragma unroll
      for (int in = 0; in < 4; ++in) {
        const int R = wc * 64 + in * 16 + qlo;
        bb[in] = *(const short8*)&Bb[R * 64 + (((ks * 4 + qhi) ^ q3) << 3)];
      }
      #pragma unroll
      for (int im = 0; im < 4; ++im)
        #pragma unroll
        for (int in = 0; in < 4; ++in)
          acc[im][in] = __builtin_amdgcn_mfma_f32_16x16x32_bf16(a[im], bb[in], acc[im][in], 0, 0, 0);
    }
  }

  const int s_idx = n0 >> 8;                  // block-constant
  const int cl0 = n0 & 255;

  #pragma unroll
  for (int im = 0; im < 4; ++im) {
    const int mloc = wr * 32 + im * 8 + qhi * 2;
    #pragma unroll
    for (int in = 0; in < 4; ++in) {
      const int nloc = wc * 64 + in * 16 + qlo;
      const int cloc = cl0 + nloc;
      #pragma unroll
      for (int pp = 0; pp < 2; ++pp) {
        const int mC = (m0 >> 1) + mloc + pp;
        float re = acc[im][in][2 * pp], iv = acc[im][in][2 * pp + 1];
        if (MODE == 1) {
          float2 tw = tab[(mC << 8) + cloc];            // E- table (coalesced)
          float r2 = re * tw.x + iv * tw.y, i2 = iv * tw.x - re * tw.y;
          outp[(size_t)((s_idx << 8) + mC) * 256 + cloc] = packbf(r2, i2);
        } else {                                        // MODE 4: final y
          const float sc = 1.0f / 65536.0f;
          float* y0 = yout + ((size_t)s_idx << 16) + (mC << 8) + cloc;
          y0[0] = re * sc;        // y[2s][c+256r]
          y0[32768] = iv * sc;    // y[2s+1][c+256r]
        }
      }
    }
  }
}

// 256^2-tile stage (MODES 2,3): 512 threads = 8 waves (2m x 4n grid), BK=64,
// double-buffered 128 KB LDS, same staging/read swizzle as dft_stage (proven).
// Grid = 256 blocks = (mt in {0,1}) x (s in [0,128)) = exactly 1 block/CU.
// Per wave: 128x64 output, acc[8][4].  K accumulation order identical to the
// 128^2 version (chunks ascending, ks ascending) -> bit-identical results.
// MODE 2: P[(s,k1)][k2-half] = C * WtT, via swizzled LDS transpose Tr[256][128].
// MODE 3: H2[(s,c)][k1] = C * Tw(E+), direct coalesced write (lanes -> k1).
template <int MODE, int KITERS>
__global__ __launch_bounds__(512, 1) void dft_stage_big(
    const unsigned short* __restrict__ Af,
    const unsigned short* __restrict__ Bd,
    uint32_t* __restrict__ outp,
    const float2* __restrict__ tab) {
  __shared__ unsigned short Sm[65536];        // A: 2x32KB | B: 2x32KB = 128 KB
  constexpr int KP = KITERS * 64;

  const int mt = blockIdx.x >> 7;             // m-half (k2- or c- half)
  const int s  = blockIdx.x & 127;
  const int m0 = mt * 256, n0 = s * 256;

  const int tid = threadIdx.x;
  const int w = tid >> 6, lane = tid & 63;
  const int qlo = lane & 15, qhi = lane >> 4;
  const int wr = w >> 2, wc = w & 3;          // 2m x 4n wave grid
  const int r8 = lane >> 3, pl = lane & 7, sj = pl ^ r8, q3 = qlo & 7;

  floatx4 acc[8][4];
  #pragma unroll
  for (int i = 0; i < 8; ++i)
    #pragma unroll
    for (int j = 0; j < 4; ++j) acc[i][j] = (floatx4){0.f, 0.f, 0.f, 0.f};

  auto issue = [&](int it, int buf) {
    const int k0 = it * 64;
    unsigned short* Asb = Sm + buf * 16384;
    unsigned short* Bsb = Sm + 32768 + buf * 16384;
    #pragma unroll
    for (int q = 0; q < 4; ++q) {
      const int R = w * 32 + q * 8 + r8;      // 8 waves x 32 rows = 256
      const unsigned short* gA = Af + (size_t)(m0 + R) * KP + k0 + sj * 8;
      const unsigned short* gB = Bd + (size_t)(n0 + R) * KP + k0 + sj * 8;
      __builtin_amdgcn_global_load_lds(
          (const __attribute__((address_space(1))) uint32_t*)gA,
          (__attribute__((address_space(3))) uint32_t*)&Asb[(w * 32 + q * 8) * 64], 16, 0, 0);
      __builtin_amdgcn_global_load_lds(
          (const __attribute__((address_space(1))) uint32_t*)gB,
          (__attribute__((address_space(3))) uint32_t*)&Bsb[(w * 32 + q * 8) * 64], 16, 0, 0);
    }
  };

  issue(0, 0);
  for (int it = 0; it < KITERS; ++it) {
    __syncthreads();                          // drains prev iter's prefetch
    if (it + 1 < KITERS) issue(it + 1, (it + 1) & 1);
    const unsigned short* Ab = Sm + (it & 1) * 16384;
    const unsigned short* Bb = Sm + 32768 + (it & 1) * 16384;
    #pragma unroll
    for (int ks = 0; ks < 2; ++ks) {
      short8 a[8], bb[4];
      #pragma unroll
      for (int im = 0; im < 8; ++im) {
        const int R = wr * 128 + im * 16 + qlo;
        a[im] = *(const short8*)&Ab[R * 64 + (((ks * 4 + qhi) ^ q3) << 3)];
      }
      #pragma unroll
      for (int in = 0; in < 4; ++in) {
        const int R = wc * 64 + in * 16 + qlo;
        bb[in] = *(const short8*)&Bb[R * 64 + (((ks * 4 + qhi) ^ q3) << 3)];
      }
      #pragma unroll
      for (int im = 0; im < 8; ++im)
        #pragma unroll
        for (int in = 0; in < 4; ++in)
          acc[im][in] = __builtin_amdgcn_mfma_f32_16x16x32_bf16(a[im], bb[in], acc[im][in], 0, 0, 0);
    }
  }

  if (MODE == 2) {
    // P_half[k1 256][k2 128] via swizzled LDS transpose (reuses all 128 KB).
    __syncthreads();
    uint32_t* Tr = (uint32_t*)Sm;             // [256][128] u32, col-XOR swizzled
    #pragma unroll
    for (int im = 0; im < 8; ++im) {
      const int mbase = wr * 64 + im * 8 + qhi * 2;
      #pragma unroll
      for (int in = 0; in < 4; ++in) {
        const int k1 = wc * 64 + in * 16 + qlo;         // = nloc
        #pragma unroll
        for (int pp = 0; pp < 2; ++pp) {
          const int mlocC = mbase + pp;                 // [0,128) local k2
          const int k2 = mt * 128 + mlocC;              // global k2
          float re = acc[im][in][2 * pp], iv = acc[im][in][2 * pp + 1];
          float2 wv = tab[(k2 << 8) + k1];              // WtT, coalesced (lanes->k1)
          float r2 = re * wv.x - iv * wv.y, i2 = re * wv.y + iv * wv.x;
          const int colsw = ((mlocC & 124) ^ ((k1 & 7) << 2)) + (mlocC & 3);
          Tr[k1 * 128 + colsw] = packbf(r2, i2);
        }
      }
    }
    __syncthreads();
    const int ln = tid >> 1, half = tid & 1;  // 256 rows x 2 half-rows
    uint32_t* dst = outp + (size_t)((s << 8) + ln) * 256 + mt * 128 + half * 64;
    #pragma unroll
    for (int j = 0; j < 64; j += 4) {
      const int grp = (half * 64 + j) ^ ((ln & 7) << 2);
      *(uint4*)(dst + j) = *(const uint4*)&Tr[ln * 128 + grp];
    }
    return;
  }

  // MODE 3: direct write, lanes -> consecutive k1 (coalesced u32 segments)
  #pragma unroll
  for (int im = 0; im < 8; ++im) {
    const int mbase = wr * 64 + im * 8 + qhi * 2;
    #pragma unroll
    for (int in = 0; in < 4; ++in) {
      const int k1 = wc * 64 + in * 16 + qlo;
      #pragma unroll
      for (int pp = 0; pp < 2; ++pp) {
        const int cC = mt * 128 + mbase + pp;           // global c
        float re = acc[im][in][2 * pp], iv = acc[im][in][2 * pp + 1];
        float2 tw = tab[(cC << 8) + k1];                // E+ table (coalesced)
        float r2 = re * tw.x - iv * tw.y, i2 = iv * tw.x + re * tw.y;
        outp[(size_t)((s << 8) + cC) * 256 + k1] = packbf(r2, i2);
      }
    }
  }
}

extern "C" void kernel_launch(void* const* d_in, const int* in_sizes, int n_in,
                              void* d_out, int out_size, void* d_ws, size_t ws_size,
                              hipStream_t stream) {
  const float* x = (const float*)d_in[0];     // [256][32768] fp32
  const float* filt = (const float*)d_in[1];  // [1][32768] fp32
  float* Y = (float*)d_out;                   // [256][32768] fp32

  char* ws = (char*)d_ws;
  unsigned short* A1 = (unsigned short*)(ws + 0);              // 256 KB
  unsigned short* A2 = (unsigned short*)(ws + 0x40000);        // 512 KB
  unsigned short* A3 = (unsigned short*)(ws + 0xC0000);        // 512 KB
  unsigned short* A4 = (unsigned short*)(ws + 0x140000);       // 256 KB
  float2* Gw  = (float2*)(ws + 0x180000);                      // 512 KB
  float2* WtT = (float2*)(ws + 0x200000);                      // 512 KB
  float2* Tw  = (float2*)(ws + 0x280000);                      // 512 KB
  unsigned short* Zp = (unsigned short*)(ws + (3u << 20));     // 16 MB  [3,19)
  unsigned short* G2 = (unsigned short*)(ws + 19922944u);      // 32 MB  [19,51)
  unsigned short* P  = (unsigned short*)(ws + 53477376u);      // 32 MB  [51,83)
  unsigned short* H2 = (unsigned short*)(ws + (3u << 20));     // 32 MB, reuses Zp+G2 (dead)

  hipLaunchKernelGGL(prep_all, dim3(4608), dim3(256), 0, stream,
                     x, filt, A1, A2, A3, A4, (uint32_t*)Zp, Gw, Tw);
  hipLaunchKernelGGL(prep_wb, dim3(256), dim3(256), 0, stream, Gw, WtT);

  hipLaunchKernelGGL((dft_stage<1, 4>), dim3(1024), dim3(256), 0, stream,
                     A1, Zp, (uint32_t*)G2, (float*)nullptr, Tw);
  hipLaunchKernelGGL((dft_stage_big<2, 8>), dim3(256), dim3(512), 0, stream,
                     A2, G2, (uint32_t*)P, WtT);
  hipLaunchKernelGGL((dft_stage_big<3, 8>), dim3(256), dim3(512), 0, stream,
                     A3, P, (uint32_t*)H2, Tw);
  hipLaunchKernelGGL((dft_stage<4, 8>), dim3(512), dim3(256), 0, stream,
                     A4, H2, (uint32_t*)nullptr, Y, Tw);
}